// Round 8
// baseline (138.568 us; speedup 1.0000x reference)
//
#include <hip/hip_runtime.h>
#include <hip/hip_bf16.h>
#include <math.h>

#define NQ 196
#define BATCH 4
#define HD 512            // H * D_K == D_MODEL
#define NH 8
#define DK 64
#define MROWS 784         // BATCH*NQ
#define MPAD 832          // 26*32: GEMM M-tile overhang rows

typedef __attribute__((ext_vector_type(8))) short short8;
typedef __attribute__((ext_vector_type(4))) short short4v;
typedef __attribute__((ext_vector_type(4))) float float4v;

__device__ __forceinline__ float b2f(short s) {
  return __uint_as_float(((unsigned)(unsigned short)s) << 16);
}
__device__ __forceinline__ short f2b(float x) {
  return __builtin_bit_cast(short, __float2bfloat16(x));
}
__device__ __forceinline__ float fexp2(float x) {
  float r; asm("v_exp_f32 %0, %1" : "=v"(r) : "v"(x)); return r;
}
__device__ __forceinline__ float frcp(float x) {
  float r; asm("v_rcp_f32 %0, %1" : "=v"(r) : "v"(x)); return r;
}
__device__ __forceinline__ void cvt4(float4 v, short4v& hi, short4v& lo) {
  float x[4] = {v.x, v.y, v.z, v.w};
  #pragma unroll
  for (int i = 0; i < 4; ++i) {
    hi[i] = f2b(x[i]);
    lo[i] = f2b(x[i] - b2f(hi[i]));
  }
}
__device__ __forceinline__ void cvt8(float4 v0, float4 v1, short8& hi, short8& lo) {
  short4v h0, l0, h1, l1;
  cvt4(v0, h0, l0); cvt4(v1, h1, l1);
  hi = short8{h0[0],h0[1],h0[2],h0[3],h1[0],h1[1],h1[2],h1[3]};
  lo = short8{l0[0],l0[1],l0[2],l0[3],l1[0],l1[1],l1[2],l1[3]};
}
__device__ __forceinline__ void gload_lds16(const void* g, void* l) {
  __builtin_amdgcn_global_load_lds(
      (const __attribute__((address_space(1))) unsigned int*)g,
      (__attribute__((address_space(3))) unsigned int*)l, 16, 0, 0);
}

// ==================== kernel 1: projections (q/k/v) =========================
// 32x64 tile, BK=64 (624 blocks, 2.4/CU for tail balance). A=X fp32 (t<256),
// B=W fp32 (all threads), reg-staged->bf16 hi/lo. 48 KB LDS, 3 blocks/CU.
// Spare z==2 blocks also split Wo -> bf16 hi/lo for kernel 3.
struct ProjArgs {
  const float* X[3]; const float* W[3]; const float* bias[3];
  float* Cf[3]; short* Ch[3]; short* Cl[3];
  const float* Wo; short* Woh; short* Wol;
};

__global__ __launch_bounds__(512)
void proj_kernel(ProjArgs a) {
  const int z = blockIdx.z;
  const float* __restrict__ X = a.X[z];
  const float* __restrict__ W = a.W[z];
  const int t = threadIdx.x;
  const int ln = t & 63, lm = ln & 15, quad = ln >> 4;
  const int w = t >> 6, wm = w >> 2, wn = w & 3;     // 2m x 4n waves, 16x16 out
  const int m0 = blockIdx.x << 5, n0 = blockIdx.y << 6;

  __shared__ __align__(16) short smem[24576];  // 48 KB: 2 buf x {Ah2k Al2k Bh4k Bl4k shorts}

  // A staging: t<256, row ra 0..31, 8 floats each.
  const bool aload = t < 256;
  const int ra = (t & 255) >> 3;
  const int cga = (t & 7) << 3;
  const int wIdxA = ra * 64 + (cga ^ ((ra & 7) << 3));
  const float* gA = X + (size_t)min(m0 + ra, MROWS - 1) * HD;   // clamp overhang
  // B staging: all 512 threads, row sr 0..63, 8 floats each.
  const int sr = t >> 3;
  const int cgb = (t & 7) << 3;
  const int wIdxB = sr * 64 + (cgb ^ ((sr & 7) << 3));
  const float* gB = W + (size_t)(n0 + sr) * HD;

  float4 ra0, ra1, rb0, rb1;
  float4v acc = {0.f,0.f,0.f,0.f};
  const int ar = (wm << 4) + lm;                // A tile row (0..31)
  const int br = (wn << 4) + lm;                // B tile row (0..63)
  const int swz = (lm & 7) << 3;

  // prologue: stage buffer 0
  if (aload) { ra0 = *(const float4*)(gA + cga);  ra1 = *(const float4*)(gA + cga + 4); }
  rb0 = *(const float4*)(gB + cgb);  rb1 = *(const float4*)(gB + cgb + 4);
  {
    short8 hi, lo;
    if (aload) {
      cvt8(ra0, ra1, hi, lo);
      *(short8*)&smem[0 + wIdxA] = hi;  *(short8*)&smem[2048 + wIdxA] = lo;
    }
    cvt8(rb0, rb1, hi, lo);
    *(short8*)&smem[4096 + wIdxB] = hi;  *(short8*)&smem[8192 + wIdxB] = lo;
  }

  for (int kt = 0; kt < 8; ++kt) {
    const int buf = (kt & 1) * 12288;
    __syncthreads();                            // buf(kt) ready
    if (kt < 7) {
      const int kb = (kt + 1) << 6;
      if (aload) { ra0 = *(const float4*)(gA + kb + cga);  ra1 = *(const float4*)(gA + kb + cga + 4); }
      rb0 = *(const float4*)(gB + kb + cgb);  rb1 = *(const float4*)(gB + kb + cgb + 4);
    }
    const short* Sb = smem + buf;
    #pragma unroll
    for (int h2 = 0; h2 < 2; ++h2) {
      const int c = (h2 << 5) + (quad << 3);
      const int cs = c ^ swz;
      short8 a_h = *(const short8*)&Sb[         ar * 64 + cs];
      short8 a_l = *(const short8*)&Sb[2048  +  ar * 64 + cs];
      short8 b_h = *(const short8*)&Sb[4096  +  br * 64 + cs];
      short8 b_l = *(const short8*)&Sb[8192  +  br * 64 + cs];
      acc = __builtin_amdgcn_mfma_f32_16x16x32_bf16(a_h, b_h, acc, 0,0,0);
      acc = __builtin_amdgcn_mfma_f32_16x16x32_bf16(a_h, b_l, acc, 0,0,0);
      acc = __builtin_amdgcn_mfma_f32_16x16x32_bf16(a_l, b_h, acc, 0,0,0);
    }
    if (kt < 7) {
      short* Nb = smem + (buf ^ 12288);
      short8 hi, lo;
      if (aload) {
        cvt8(ra0, ra1, hi, lo);
        *(short8*)&Nb[0 + wIdxA] = hi;  *(short8*)&Nb[2048 + wIdxA] = lo;
      }
      cvt8(rb0, rb1, hi, lo);
      *(short8*)&Nb[4096 + wIdxB] = hi;  *(short8*)&Nb[8192 + wIdxB] = lo;
    }
  }

  // epilogue: bias, fp32 store (+ bf16 hi/lo split for q/k)
  {
    const float* bias = a.bias[z];
    float* Cf = a.Cf[z]; short* Ch = a.Ch[z]; short* Cl = a.Cl[z];
    const int n = n0 + (wn << 4) + lm;
    const float bv = bias[n];
    #pragma unroll
    for (int r = 0; r < 4; ++r) {
      const int m = m0 + (wm << 4) + (quad << 2) + r;   // < MPAD always
      const float c = acc[r] + bv;
      Cf[(size_t)m * HD + n] = c;
      if (Ch) {
        const short hi = f2b(c);
        Ch[(size_t)m * HD + n] = hi;
        Cl[(size_t)m * HD + n] = f2b(c - b2f(hi));
      }
    }
  }

  // Wo split (64 of the 208 z==2 blocks; independent of the GEMM above)
  if (z == 2) {
    const int lin = blockIdx.y * 26 + blockIdx.x;
    if (lin < 64) {
      const size_t off = (size_t)lin * 4096 + (size_t)t * 8;
      float4 v0 = *(const float4*)(a.Wo + off);
      float4 v1 = *(const float4*)(a.Wo + off + 4);
      short8 hi, lo; cvt8(v0, v1, hi, lo);
      *(short8*)(a.Woh + off) = hi;
      *(short8*)(a.Wol + off) = lo;
    }
  }
}

// ======== kernel 2: fused attention, 256 thr (4 waves) ======================
// One block per (q-tile 16, h, b); wave w owns q-rows 4w..4w+3 end-to-end:
// softmax then full-k gated PV on the same rows -> no inter-wave reduction,
// no barrier after softmax. LDS = S only (13.6 KB); 8 blocks/CU (wave-limit).
__global__ __launch_bounds__(256)
void attn_fused(const short* __restrict__ qsh, const short* __restrict__ qsl,
                const short* __restrict__ ksh, const short* __restrict__ ksl,
                const float* __restrict__ qsg, const float* __restrict__ kpg,
                const float* __restrict__ vpg, const float* __restrict__ scg,
                short* __restrict__ imgh, short* __restrict__ imgl) {
  const int q0 = blockIdx.x * 16;
  const int h  = blockIdx.y;
  const int b  = blockIdx.z;
  const int t  = threadIdx.x;
  const int w = t >> 6, ln = t & 63;
  const int lm = ln & 15, quad = ln >> 4;
  const float L2E = 1.4426950408889634f;

  __shared__ __align__(16) float S[16][212];  // 13.6 KB (16B-aligned rows)

  // ---- phase 1: S = q_sig . k_p^T (bf16x3 MFMA), waves stride nt by 4 ----
  const size_t abase = ((size_t)(b * NQ) + q0 + lm) * HD + h * DK + (quad << 3);
  short8 ah0 = *(const short8*)(qsh + abase);
  short8 ah1 = *(const short8*)(qsh + abase + 32);
  short8 al0 = *(const short8*)(qsl + abase);
  short8 al1 = *(const short8*)(qsl + abase + 32);

  for (int nt = w; nt < 13; nt += 4) {
    const size_t bbase = ((size_t)(b * NQ) + nt * 16 + lm) * HD + h * DK + (quad << 3);
    short8 bh0 = *(const short8*)(ksh + bbase);
    short8 bh1 = *(const short8*)(ksh + bbase + 32);
    short8 bl0 = *(const short8*)(ksl + bbase);
    short8 bl1 = *(const short8*)(ksl + bbase + 32);
    float4v acc = {0.f, 0.f, 0.f, 0.f};
    acc = __builtin_amdgcn_mfma_f32_16x16x32_bf16(ah0, bh0, acc, 0,0,0);
    acc = __builtin_amdgcn_mfma_f32_16x16x32_bf16(ah1, bh1, acc, 0,0,0);
    acc = __builtin_amdgcn_mfma_f32_16x16x32_bf16(ah0, bl0, acc, 0,0,0);
    acc = __builtin_amdgcn_mfma_f32_16x16x32_bf16(ah1, bl1, acc, 0,0,0);
    acc = __builtin_amdgcn_mfma_f32_16x16x32_bf16(al0, bh0, acc, 0,0,0);
    acc = __builtin_amdgcn_mfma_f32_16x16x32_bf16(al1, bh1, acc, 0,0,0);
    #pragma unroll
    for (int r = 0; r < 4; ++r)
      S[(quad << 2) + r][nt * 16 + lm] = acc[r];
  }
  __syncthreads();                             // S complete (cross-wave cols)

  // ---- phase 2: softmax in place; wave w -> rows 4w..4w+3 ----
  #pragma unroll
  for (int i = 0; i < 4; ++i) {
    const int rr = (w << 2) + i;
    const int q = q0 + rr;
    const bool qok = q < NQ;
    const float* srow = scg + ((size_t)h * NQ + (qok ? q : 0)) * NQ;
    float att[4];
    #pragma unroll
    for (int j = 0; j < 4; ++j) {
      const int c = ln + (j << 6);
      att[j] = -1e30f;
      if (c < NQ) att[j] = S[rr][c] * srow[c] * L2E;
    }
    float m = fmaxf(fmaxf(att[0], att[1]), fmaxf(att[2], att[3]));
    #pragma unroll
    for (int off = 32; off; off >>= 1) m = fmaxf(m, __shfl_xor(m, off, 64));
    float e[4], s = 0.f;
    #pragma unroll
    for (int j = 0; j < 4; ++j) { e[j] = fexp2(att[j] - m); s += e[j]; }
    #pragma unroll
    for (int off = 32; off; off >>= 1) s += __shfl_xor(s, off, 64);
    const float rinv = __fdividef(1.f, s);
    #pragma unroll
    for (int j = 0; j < 4; ++j) {
      const int c = ln + (j << 6);
      if (c < NQ) S[rr][c] = e[j] * rinv;
    }
  }
  // no barrier: phase 3 reads only this wave's own rows of S

  // ---- phase 3: gated PV, full k range; wave w -> rows 4w..4w+3 ----
  {
    const int d = ln;
    const int qg = w << 2;
    const float LOG2E = 1.4426950408889634f;

    float nqs[4];
    #pragma unroll
    for (int qi = 0; qi < 4; ++qi) {
      const int row = min(b * NQ + q0 + qg + qi, MROWS - 1);  // clamp overhang
      nqs[qi] = -qsg[(size_t)row * HD + h * DK + d] * LOG2E;
    }
    const float* kp = kpg + ((size_t)(b * NQ)) * HD + h * DK + d;
    const float* vp = vpg + ((size_t)(b * NQ)) * HD + h * DK + d;

    float acc[4] = {0.f, 0.f, 0.f, 0.f};

    for (int k = 0; k < NQ; k += 4) {
      const float kv0 = kp[(size_t)(k + 0) * HD];
      const float kv1 = kp[(size_t)(k + 1) * HD];
      const float kv2 = kp[(size_t)(k + 2) * HD];
      const float kv3 = kp[(size_t)(k + 3) * HD];
      const float vv0 = vp[(size_t)(k + 0) * HD];
      const float vv1 = vp[(size_t)(k + 1) * HD];
      const float vv2 = vp[(size_t)(k + 2) * HD];
      const float vv3 = vp[(size_t)(k + 3) * HD];
      #pragma unroll
      for (int qi = 0; qi < 4; ++qi) {
        const float4 s4 = *(const float4*)&S[qg + qi][k];
        acc[qi] += s4.x * (vv0 * frcp(1.f + fexp2(nqs[qi] * kv0)));
        acc[qi] += s4.y * (vv1 * frcp(1.f + fexp2(nqs[qi] * kv1)));
        acc[qi] += s4.z * (vv2 * frcp(1.f + fexp2(nqs[qi] * kv2)));
        acc[qi] += s4.w * (vv3 * frcp(1.f + fexp2(nqs[qi] * kv3)));
      }
    }

    // write image rows directly (wave-local, no reduction)
    #pragma unroll
    for (int qi = 0; qi < 4; ++qi) {
      const int q = q0 + qg + qi;
      if (q < NQ) {
        const size_t o = ((size_t)(b * NQ) + q) * HD + h * DK + d;
        const short hi = f2b(acc[qi]);
        imgh[o] = hi;
        imgl[o] = f2b(acc[qi] - b2f(hi));
      }
    }
  }
}

// ======== kernel 3: out = image @ Wo^T + bo, gated; all-DMA 32x64 tile ======
// 208 blocks (26 m-tiles x 8 n-tiles); 48 KB LDS.  (R6 proven version.)
__global__ __launch_bounds__(512)
void out_kernel(const short* __restrict__ Ahp, const short* __restrict__ Alp,
                const short* __restrict__ Bhp, const short* __restrict__ Blp,
                const float* __restrict__ bo, const float* __restrict__ q_sig,
                float* __restrict__ out) {
  __shared__ short smem[24576];      // 48 KB: 2 buf x {Ah 2k, Al 2k, Bh 4k, Bl 4k}
  const int t = threadIdx.x;
  const int ln = t & 63, lm = ln & 15, quad = ln >> 4;
  const int w = t >> 6;
  const int wm = w >> 2, wn = w & 3;           // 2m x 4n waves, 16x16 out each
  const int m0 = blockIdx.x << 5, n0 = blockIdx.y << 6;

  // B staging: all 512 threads, row sr=t>>3, pre-swizzled source col.
  const int sr = t >> 3;
  const int sc = ((t & 7) ^ (sr & 7)) << 3;
  const short* gB_h = Bhp + (size_t)(n0 + sr) * HD + sc;
  const short* gB_l = Blp + (size_t)(n0 + sr) * HD + sc;
  // A staging: waves 0-3 hi, waves 4-7 lo; row ra=tt>>3 (0..31).
  const int tt = t & 255;
  const int ra = tt >> 3;
  const int sca = ((tt & 7) ^ (ra & 7)) << 3;
  const short* gA = ((t < 256) ? Ahp : Alp) + (size_t)(m0 + ra) * HD + sca;
  const int aoff = (t < 256) ? 0 : 2048;        // Ah / Al base (shorts)
  const int ldstA = aoff + tt * 8;
  const int ldstB = t * 8;

  float4v acc = {0.f,0.f,0.f,0.f};

  gload_lds16(gA,   &smem[ldstA]);
  gload_lds16(gB_h, &smem[4096 + ldstB]);
  gload_lds16(gB_l, &smem[8192 + ldstB]);

  const int ar = (wm << 4) + lm;                // A tile row (0..31)
  const int br = (wn << 4) + lm;                // B tile row (0..63)
  const int swz = (lm & 7) << 3;

  for (int kt = 0; kt < 8; ++kt) {
    const int buf = kt & 1;
    __syncthreads();                            // buf ready (DMA drained)
    if (kt < 7) {
      const int kb = (kt + 1) << 6;
      short* nb = &smem[(buf ^ 1) * 12288];
      gload_lds16(gA + kb,   &nb[ldstA]);
      gload_lds16(gB_h + kb, &nb[4096 + ldstB]);
      gload_lds16(gB_l + kb, &nb[8192 + ldstB]);
    }
    const short* Sb = &smem[buf * 12288];
    #pragma unroll
    for (int h2 = 0; h2 < 2; ++h2) {
      const int c = (h2 << 5) + (quad << 3);
      const int cs = c ^ swz;
      short8 a_h = *(const short8*)&Sb[         ar * 64 + cs];
      short8 a_l = *(const short8*)&Sb[2048  +  ar * 64 + cs];
      short8 b_h = *(const short8*)&Sb[4096  +  br * 64 + cs];
      short8 b_l = *(const short8*)&Sb[8192  +  br * 64 + cs];
      acc = __builtin_amdgcn_mfma_f32_16x16x32_bf16(a_h, b_h, acc, 0,0,0);
      acc = __builtin_amdgcn_mfma_f32_16x16x32_bf16(a_h, b_l, acc, 0,0,0);
      acc = __builtin_amdgcn_mfma_f32_16x16x32_bf16(a_l, b_h, acc, 0,0,0);
    }
  }

  {
    const int n = n0 + (wn << 4) + lm;
    const float bv = bo[n];
    #pragma unroll
    for (int r = 0; r < 4; ++r) {
      const int m = m0 + (wm << 4) + (quad << 2) + r;
      if (m < MROWS) {
        float c = acc[r] + bv;
        const float qg = q_sig[(size_t)m * HD + n];
        c = __fdividef(c, 1.f + __expf(-qg * c));  // sigmoid(qg*c)*c
        out[(size_t)m * HD + n] = c;
      }
    }
  }
}

extern "C" void kernel_launch(void* const* d_in, const int* in_sizes, int n_in,
                              void* d_out, int out_size, void* d_ws, size_t ws_size,
                              hipStream_t stream) {
  const float* queries = (const float*)d_in[0];
  const float* keys    = (const float*)d_in[1];
  const float* values  = (const float*)d_in[2];
  const float* Wq = (const float*)d_in[3];
  const float* bq = (const float*)d_in[4];
  const float* Wk = (const float*)d_in[5];
  const float* bk = (const float*)d_in[6];
  const float* Wv = (const float*)d_in[7];
  const float* bv = (const float*)d_in[8];
  const float* Wo = (const float*)d_in[9];
  const float* bo = (const float*)d_in[10];
  const float* scale = (const float*)d_in[11];

  char* base = (char*)d_ws;
  const size_t NELPS = (size_t)MPAD * HD;    // 425984
  const size_t WEL   = (size_t)HD * HD;      // 262144

  size_t o = 0;
  float* q_sig = (float*)(base + o); o += NELPS * 4;
  float* k_p   = (float*)(base + o); o += NELPS * 4;
  float* v_p   = (float*)(base + o); o += NELPS * 4;
  short* qsh = (short*)(base + o); o += NELPS * 2;
  short* qsl = (short*)(base + o); o += NELPS * 2;
  short* ksh = (short*)(base + o); o += NELPS * 2;
  short* ksl = (short*)(base + o); o += NELPS * 2;
  short* imgh = (short*)(base + o); o += NELPS * 2;
  short* imgl = (short*)(base + o); o += NELPS * 2;
  short* Woh = (short*)(base + o); o += WEL * 2;
  short* Wol = (short*)(base + o); o += WEL * 2;

  // 1) projections + weight splits
  ProjArgs p;
  p.X[0] = queries; p.X[1] = keys; p.X[2] = values;
  p.W[0] = Wq;      p.W[1] = Wk;   p.W[2] = Wv;
  p.bias[0] = bq;   p.bias[1] = bk; p.bias[2] = bv;
  p.Cf[0] = q_sig;  p.Cf[1] = k_p;  p.Cf[2] = v_p;
  p.Ch[0] = qsh; p.Cl[0] = qsl;
  p.Ch[1] = ksh; p.Cl[1] = ksl;
  p.Ch[2] = nullptr; p.Cl[2] = nullptr;
  p.Wo = Wo; p.Woh = Woh; p.Wol = Wol;
  proj_kernel<<<dim3(MPAD/32, HD/64, 3), 512, 0, stream>>>(p);

  // 2) fused scores + softmax + gated PV -> image (bf16 hi/lo)
  attn_fused<<<dim3(13, NH, BATCH), 256, 0, stream>>>(
      qsh, qsl, ksh, ksl, q_sig, k_p, v_p, scale, imgh, imgl);

  // 3) out = image @ Wo^T + bo, gated by q_sig
  out_kernel<<<dim3(MPAD/32, HD/64), 512, 0, stream>>>(
      imgh, imgl, Woh, Wol, bo, q_sig, (float*)d_out);
}

// Round 9
// 135.351 us; speedup vs baseline: 1.0238x; 1.0238x over previous
//
#include <hip/hip_runtime.h>
#include <hip/hip_bf16.h>
#include <math.h>

#define NQ 196
#define BATCH 4
#define HD 512            // H * D_K == D_MODEL
#define NH 8
#define DK 64
#define MROWS 784         // BATCH*NQ
#define MPAD 832          // GEMM M-tile overhang rows

typedef __attribute__((ext_vector_type(8))) short short8;
typedef __attribute__((ext_vector_type(4))) short short4v;
typedef __attribute__((ext_vector_type(4))) float float4v;

__device__ __forceinline__ float b2f(short s) {
  return __uint_as_float(((unsigned)(unsigned short)s) << 16);
}
__device__ __forceinline__ short f2b(float x) {
  return __builtin_bit_cast(short, __float2bfloat16(x));
}
__device__ __forceinline__ float fexp2(float x) {
  float r; asm("v_exp_f32 %0, %1" : "=v"(r) : "v"(x)); return r;
}
__device__ __forceinline__ float frcp(float x) {
  float r; asm("v_rcp_f32 %0, %1" : "=v"(r) : "v"(x)); return r;
}
__device__ __forceinline__ void cvt4(float4 v, short4v& hi, short4v& lo) {
  float x[4] = {v.x, v.y, v.z, v.w};
  #pragma unroll
  for (int i = 0; i < 4; ++i) {
    hi[i] = f2b(x[i]);
    lo[i] = f2b(x[i] - b2f(hi[i]));
  }
}
__device__ __forceinline__ void cvt8(float4 v0, float4 v1, short8& hi, short8& lo) {
  short4v h0, l0, h1, l1;
  cvt4(v0, h0, l0); cvt4(v1, h1, l1);
  hi = short8{h0[0],h0[1],h0[2],h0[3],h1[0],h1[1],h1[2],h1[3]};
  lo = short8{l0[0],l0[1],l0[2],l0[3],l1[0],l1[1],l1[2],l1[3]};
}
__device__ __forceinline__ void gload_lds16(const void* g, void* l) {
  __builtin_amdgcn_global_load_lds(
      (const __attribute__((address_space(1))) unsigned int*)g,
      (__attribute__((address_space(3))) unsigned int*)l, 16, 0, 0);
}

// ==================== kernel 1: projections (q/k/v) =========================
// 64x64 tile, BK=64, A=X fp32 reg-staged->bf16 hi/lo, B=W fp32 reg-staged.
// Spare z==2 blocks also split Wo -> bf16 hi/lo for kernel 3.  (R6 proven.)
struct ProjArgs {
  const float* X[3]; const float* W[3]; const float* bias[3];
  float* Cf[3]; short* Ch[3]; short* Cl[3];
  const float* Wo; short* Woh; short* Wol;
};

__global__ __launch_bounds__(512)
void proj_kernel(ProjArgs a) {
  const int z = blockIdx.z;
  const float* __restrict__ X = a.X[z];
  const float* __restrict__ W = a.W[z];
  const int t = threadIdx.x;
  const int ln = t & 63, lm = ln & 15, quad = ln >> 4;
  const int w = t >> 6, wm = w >> 1, wn = w & 1;
  const int m0 = blockIdx.x << 6, n0 = blockIdx.y << 6;

  __shared__ __align__(16) short smem[32768];   // 64 KB, 2 buffers

  const int sr = t >> 3;                       // staged row 0..63
  const int cg = (t & 7) << 3;                 // col group (8 floats)
  const int wIdx = sr * 64 + (cg ^ ((sr & 7) << 3));   // swizzled LDS slot
  const float* gA = X + (size_t)min(m0 + sr, MROWS - 1) * HD;   // clamp overhang
  const float* gB = W + (size_t)(n0 + sr) * HD;

  float4 ra0, ra1, rb0, rb1;
  float4v acc0 = {0.f,0.f,0.f,0.f}, acc1 = {0.f,0.f,0.f,0.f};
  const int ar = (wm << 4) + lm;
  const int br0 = (wn << 5) + lm, br1 = br0 + 16;
  const int swz = (lm & 7) << 3;

  // prologue: stage buffer 0
  ra0 = *(const float4*)(gA + cg);     ra1 = *(const float4*)(gA + cg + 4);
  rb0 = *(const float4*)(gB + cg);     rb1 = *(const float4*)(gB + cg + 4);
  {
    short8 hi, lo;
    cvt8(ra0, ra1, hi, lo);
    *(short8*)&smem[0    + wIdx] = hi;  *(short8*)&smem[4096  + wIdx] = lo;
    cvt8(rb0, rb1, hi, lo);
    *(short8*)&smem[8192 + wIdx] = hi;  *(short8*)&smem[12288 + wIdx] = lo;
  }

  for (int kt = 0; kt < 8; ++kt) {
    const int buf = kt & 1;
    __syncthreads();                            // buf(kt) ready
    if (kt < 7) {
      const int kb = (kt + 1) << 6;
      ra0 = *(const float4*)(gA + kb + cg);  ra1 = *(const float4*)(gA + kb + cg + 4);
      rb0 = *(const float4*)(gB + kb + cg);  rb1 = *(const float4*)(gB + kb + cg + 4);
    }
    const short* Sb = smem + (buf << 14);
    #pragma unroll
    for (int h2 = 0; h2 < 2; ++h2) {
      const int c = (h2 << 5) + (quad << 3);
      const int cs = c ^ swz;
      short8 a_h = *(const short8*)&Sb[         ar  * 64 + cs];
      short8 a_l = *(const short8*)&Sb[4096  +  ar  * 64 + cs];
      short8 b0h = *(const short8*)&Sb[8192  +  br0 * 64 + cs];
      short8 b0l = *(const short8*)&Sb[12288 +  br0 * 64 + cs];
      short8 b1h = *(const short8*)&Sb[8192  +  br1 * 64 + cs];
      short8 b1l = *(const short8*)&Sb[12288 +  br1 * 64 + cs];
      acc0 = __builtin_amdgcn_mfma_f32_16x16x32_bf16(a_h, b0h, acc0, 0,0,0);
      acc0 = __builtin_amdgcn_mfma_f32_16x16x32_bf16(a_h, b0l, acc0, 0,0,0);
      acc0 = __builtin_amdgcn_mfma_f32_16x16x32_bf16(a_l, b0h, acc0, 0,0,0);
      acc1 = __builtin_amdgcn_mfma_f32_16x16x32_bf16(a_h, b1h, acc1, 0,0,0);
      acc1 = __builtin_amdgcn_mfma_f32_16x16x32_bf16(a_h, b1l, acc1, 0,0,0);
      acc1 = __builtin_amdgcn_mfma_f32_16x16x32_bf16(a_l, b1h, acc1, 0,0,0);
    }
    if (kt < 7) {
      short* Nb = smem + ((buf ^ 1) << 14);
      short8 hi, lo;
      cvt8(ra0, ra1, hi, lo);
      *(short8*)&Nb[0    + wIdx] = hi;  *(short8*)&Nb[4096  + wIdx] = lo;
      cvt8(rb0, rb1, hi, lo);
      *(short8*)&Nb[8192 + wIdx] = hi;  *(short8*)&Nb[12288 + wIdx] = lo;
    }
  }

  // epilogue: bias, fp32 store (+ bf16 hi/lo split for q/k)
  {
    const float* bias = a.bias[z];
    float* Cf = a.Cf[z]; short* Ch = a.Ch[z]; short* Cl = a.Cl[z];
    #pragma unroll
    for (int nf = 0; nf < 2; ++nf) {
      const float4v av = nf ? acc1 : acc0;
      const int n = n0 + (wn << 5) + (nf << 4) + lm;
      const float bv = bias[n];
      #pragma unroll
      for (int r = 0; r < 4; ++r) {
        const int m = m0 + (wm << 4) + (quad << 2) + r;   // < MPAD always
        const float c = av[r] + bv;
        Cf[(size_t)m * HD + n] = c;
        if (Ch) {
          const short hi = f2b(c);
          Ch[(size_t)m * HD + n] = hi;
          Cl[(size_t)m * HD + n] = f2b(c - b2f(hi));
        }
      }
    }
  }

  // Wo split (64 of the 104 z==2 blocks; independent of the GEMM above)
  if (z == 2) {
    const int lin = blockIdx.y * 13 + blockIdx.x;
    if (lin < 64) {
      const size_t off = (size_t)lin * 4096 + (size_t)t * 8;
      float4 v0 = *(const float4*)(a.Wo + off);
      float4 v1 = *(const float4*)(a.Wo + off + 4);
      short8 hi, lo; cvt8(v0, v1, hi, lo);
      *(short8*)(a.Woh + off) = hi;
      *(short8*)(a.Wol + off) = lo;
    }
  }
}

// ======== kernel 2: fused attention, d-split: block = (q-tile, h, b, d-half) =
// 832 blocks, 512 thr. Phases 1-2 (S via MFMA, softmax) run on full DK
// (duplicated per d-half -- MFMA util is <1%, duplication is free).
// Phase 3: q-quad = w>>1 (wave-uniform), k-quarter = 2*(w&1)+(lane>>5),
// d = dh*32 + (lane&31). Per-thread trans chain halves vs R6; ~2x waves/CU.
__global__ __launch_bounds__(512)
void attn_fused(const short* __restrict__ qsh, const short* __restrict__ qsl,
                const short* __restrict__ ksh, const short* __restrict__ ksl,
                const float* __restrict__ qsg, const float* __restrict__ kpg,
                const float* __restrict__ vpg, const float* __restrict__ scg,
                short* __restrict__ imgh, short* __restrict__ imgl) {
  const int q0 = blockIdx.x * 16;
  const int h  = blockIdx.y;
  const int b  = blockIdx.z >> 1;
  const int dh = blockIdx.z & 1;               // d-half
  const int t  = threadIdx.x;
  const int w = t >> 6, ln = t & 63;
  const int lm = ln & 15, quad = ln >> 4;
  const float L2E = 1.4426950408889634f;

  __shared__ __align__(16) float S[16][212];   // 13.6 KB (16B-aligned rows)
  __shared__ float R4[4][16][32];              // 8 KB: k-quarter partials

  // ---- phase 1: S = q_sig . k_p^T (bf16x3 MFMA), waves stride nt by 8 ----
  const size_t abase = ((size_t)(b * NQ) + q0 + lm) * HD + h * DK + (quad << 3);
  short8 ah0 = *(const short8*)(qsh + abase);
  short8 ah1 = *(const short8*)(qsh + abase + 32);
  short8 al0 = *(const short8*)(qsl + abase);
  short8 al1 = *(const short8*)(qsl + abase + 32);

  for (int nt = w; nt < 13; nt += 8) {
    const size_t bbase = ((size_t)(b * NQ) + nt * 16 + lm) * HD + h * DK + (quad << 3);
    short8 bh0 = *(const short8*)(ksh + bbase);
    short8 bh1 = *(const short8*)(ksh + bbase + 32);
    short8 bl0 = *(const short8*)(ksl + bbase);
    short8 bl1 = *(const short8*)(ksl + bbase + 32);
    float4v acc = {0.f, 0.f, 0.f, 0.f};
    acc = __builtin_amdgcn_mfma_f32_16x16x32_bf16(ah0, bh0, acc, 0,0,0);
    acc = __builtin_amdgcn_mfma_f32_16x16x32_bf16(ah1, bh1, acc, 0,0,0);
    acc = __builtin_amdgcn_mfma_f32_16x16x32_bf16(ah0, bl0, acc, 0,0,0);
    acc = __builtin_amdgcn_mfma_f32_16x16x32_bf16(ah1, bl1, acc, 0,0,0);
    acc = __builtin_amdgcn_mfma_f32_16x16x32_bf16(al0, bh0, acc, 0,0,0);
    acc = __builtin_amdgcn_mfma_f32_16x16x32_bf16(al1, bh1, acc, 0,0,0);
    #pragma unroll
    for (int r = 0; r < 4; ++r)
      S[(quad << 2) + r][nt * 16 + lm] = acc[r];
  }
  __syncthreads();

  // ---- phase 2: softmax in place (wave w: rows 2w, 2w+1) ----
  for (int i = 0; i < 2; ++i) {
    const int rr = (w << 1) + i;
    const int q = q0 + rr;
    const bool qok = q < NQ;
    const float* srow = scg + ((size_t)h * NQ + (qok ? q : 0)) * NQ;
    float att[4];
    #pragma unroll
    for (int j = 0; j < 4; ++j) {
      const int c = ln + (j << 6);
      att[j] = -1e30f;
      if (c < NQ) att[j] = S[rr][c] * srow[c] * L2E;
    }
    float m = fmaxf(fmaxf(att[0], att[1]), fmaxf(att[2], att[3]));
    #pragma unroll
    for (int off = 32; off; off >>= 1) m = fmaxf(m, __shfl_xor(m, off, 64));
    float e[4], s = 0.f;
    #pragma unroll
    for (int j = 0; j < 4; ++j) { e[j] = fexp2(att[j] - m); s += e[j]; }
    #pragma unroll
    for (int off = 32; off; off >>= 1) s += __shfl_xor(s, off, 64);
    const float rinv = __fdividef(1.f, s);
    #pragma unroll
    for (int j = 0; j < 4; ++j) {
      const int c = ln + (j << 6);
      if (c < NQ) S[rr][c] = e[j] * rinv;
    }
  }
  __syncthreads();

  // ---- phase 3: gated PV. q-quad = w>>1; k-quarter = 2*(w&1)+(ln>>5);
  //      d = dh*32 + (ln&31). k-quarters {48,48,48,52} keep S float4-aligned.
  {
    const int qg = (w >> 1) << 2;               // 0,4,8,12 (wave-uniform)
    const int kq = ((w & 1) << 1) | (ln >> 5);  // 0..3 (per half-wave)
    const int dd = ln & 31;
    const int d  = (dh << 5) + dd;
    const int kbeg = kq * 48;
    const int kend = (kq == 3) ? NQ : kbeg + 48;
    const float LOG2E = 1.4426950408889634f;

    float nqs[4];
    #pragma unroll
    for (int qi = 0; qi < 4; ++qi) {
      const int row = min(b * NQ + q0 + qg + qi, MROWS - 1);  // clamp overhang
      nqs[qi] = -qsg[(size_t)row * HD + h * DK + d] * LOG2E;
    }
    const float* kp = kpg + ((size_t)(b * NQ)) * HD + h * DK + d;
    const float* vp = vpg + ((size_t)(b * NQ)) * HD + h * DK + d;

    float acc[4] = {0.f, 0.f, 0.f, 0.f};

    for (int k = kbeg; k < kend; k += 4) {
      const float kv0 = kp[(size_t)(k + 0) * HD];
      const float kv1 = kp[(size_t)(k + 1) * HD];
      const float kv2 = kp[(size_t)(k + 2) * HD];
      const float kv3 = kp[(size_t)(k + 3) * HD];
      const float vv0 = vp[(size_t)(k + 0) * HD];
      const float vv1 = vp[(size_t)(k + 1) * HD];
      const float vv2 = vp[(size_t)(k + 2) * HD];
      const float vv3 = vp[(size_t)(k + 3) * HD];
      #pragma unroll
      for (int qi = 0; qi < 4; ++qi) {
        const float4 s4 = *(const float4*)&S[qg + qi][k];
        acc[qi] += s4.x * (vv0 * frcp(1.f + fexp2(nqs[qi] * kv0)));
        acc[qi] += s4.y * (vv1 * frcp(1.f + fexp2(nqs[qi] * kv1)));
        acc[qi] += s4.z * (vv2 * frcp(1.f + fexp2(nqs[qi] * kv2)));
        acc[qi] += s4.w * (vv3 * frcp(1.f + fexp2(nqs[qi] * kv3)));
      }
    }
    #pragma unroll
    for (int qi = 0; qi < 4; ++qi) R4[kq][qg + qi][dd] = acc[qi];
  }
  __syncthreads();

  // reduce the 4 k-quarters, write image (this block's d-half only)
  {
    const int qi = t >> 5, dd = t & 31;         // 512 thr = 16 q x 32 d
    const int q = q0 + qi;
    if (q < NQ) {
      const float s = R4[0][qi][dd] + R4[1][qi][dd] + R4[2][qi][dd] + R4[3][qi][dd];
      const size_t o = ((size_t)(b * NQ) + q) * HD + h * DK + (dh << 5) + dd;
      const short hi = f2b(s);
      imgh[o] = hi;
      imgl[o] = f2b(s - b2f(hi));
    }
  }
}

// ======== kernel 3: out = image @ Wo^T + bo, gated; all-DMA 32x64 tile ======
// 208 blocks (26 m-tiles x 8 n-tiles); 48 KB LDS.  (R6 proven version.)
__global__ __launch_bounds__(512)
void out_kernel(const short* __restrict__ Ahp, const short* __restrict__ Alp,
                const short* __restrict__ Bhp, const short* __restrict__ Blp,
                const float* __restrict__ bo, const float* __restrict__ q_sig,
                float* __restrict__ out) {
  __shared__ short smem[24576];      // 48 KB: 2 buf x {Ah 2k, Al 2k, Bh 4k, Bl 4k}
  const int t = threadIdx.x;
  const int ln = t & 63, lm = ln & 15, quad = ln >> 4;
  const int w = t >> 6;
  const int wm = w >> 2, wn = w & 3;           // 2m x 4n waves, 16x16 out each
  const int m0 = blockIdx.x << 5, n0 = blockIdx.y << 6;

  // B staging: all 512 threads, row sr=t>>3, pre-swizzled source col.
  const int sr = t >> 3;
  const int sc = ((t & 7) ^ (sr & 7)) << 3;
  const short* gB_h = Bhp + (size_t)(n0 + sr) * HD + sc;
  const short* gB_l = Blp + (size_t)(n0 + sr) * HD + sc;
  // A staging: waves 0-3 hi, waves 4-7 lo; row ra=tt>>3 (0..31).
  const int tt = t & 255;
  const int ra = tt >> 3;
  const int sca = ((tt & 7) ^ (ra & 7)) << 3;
  const short* gA = ((t < 256) ? Ahp : Alp) + (size_t)(m0 + ra) * HD + sca;
  const int aoff = (t < 256) ? 0 : 2048;        // Ah / Al base (shorts)
  const int ldstA = aoff + tt * 8;
  const int ldstB = t * 8;

  float4v acc = {0.f,0.f,0.f,0.f};

  gload_lds16(gA,   &smem[ldstA]);
  gload_lds16(gB_h, &smem[4096 + ldstB]);
  gload_lds16(gB_l, &smem[8192 + ldstB]);

  const int ar = (wm << 4) + lm;                // A tile row (0..31)
  const int br = (wn << 4) + lm;                // B tile row (0..63)
  const int swz = (lm & 7) << 3;

  for (int kt = 0; kt < 8; ++kt) {
    const int buf = kt & 1;
    __syncthreads();                            // buf ready (DMA drained)
    if (kt < 7) {
      const int kb = (kt + 1) << 6;
      short* nb = &smem[(buf ^ 1) * 12288];
      gload_lds16(gA + kb,   &nb[ldstA]);
      gload_lds16(gB_h + kb, &nb[4096 + ldstB]);
      gload_lds16(gB_l + kb, &nb[8192 + ldstB]);
    }
    const short* Sb = &smem[buf * 12288];
    #pragma unroll
    for (int h2 = 0; h2 < 2; ++h2) {
      const int c = (h2 << 5) + (quad << 3);
      const int cs = c ^ swz;
      short8 a_h = *(const short8*)&Sb[         ar * 64 + cs];
      short8 a_l = *(const short8*)&Sb[2048  +  ar * 64 + cs];
      short8 b_h = *(const short8*)&Sb[4096  +  br * 64 + cs];
      short8 b_l = *(const short8*)&Sb[8192  +  br * 64 + cs];
      acc = __builtin_amdgcn_mfma_f32_16x16x32_bf16(a_h, b_h, acc, 0,0,0);
      acc = __builtin_amdgcn_mfma_f32_16x16x32_bf16(a_h, b_l, acc, 0,0,0);
      acc = __builtin_amdgcn_mfma_f32_16x16x32_bf16(a_l, b_h, acc, 0,0,0);
    }
  }

  {
    const int n = n0 + (wn << 4) + lm;
    const float bv = bo[n];
    #pragma unroll
    for (int r = 0; r < 4; ++r) {
      const int m = m0 + (wm << 4) + (quad << 2) + r;
      if (m < MROWS) {
        float c = acc[r] + bv;
        const float qg = q_sig[(size_t)m * HD + n];
        c = __fdividef(c, 1.f + __expf(-qg * c));  // sigmoid(qg*c)*c
        out[(size_t)m * HD + n] = c;
      }
    }
  }
}

extern "C" void kernel_launch(void* const* d_in, const int* in_sizes, int n_in,
                              void* d_out, int out_size, void* d_ws, size_t ws_size,
                              hipStream_t stream) {
  const float* queries = (const float*)d_in[0];
  const float* keys    = (const float*)d_in[1];
  const float* values  = (const float*)d_in[2];
  const float* Wq = (const float*)d_in[3];
  const float* bq = (const float*)d_in[4];
  const float* Wk = (const float*)d_in[5];
  const float* bk = (const float*)d_in[6];
  const float* Wv = (const float*)d_in[7];
  const float* bv = (const float*)d_in[8];
  const float* Wo = (const float*)d_in[9];
  const float* bo = (const float*)d_in[10];
  const float* scale = (const float*)d_in[11];

  char* base = (char*)d_ws;
  const size_t NELPS = (size_t)MPAD * HD;    // 425984
  const size_t WEL   = (size_t)HD * HD;      // 262144

  size_t o = 0;
  float* q_sig = (float*)(base + o); o += NELPS * 4;
  float* k_p   = (float*)(base + o); o += NELPS * 4;
  float* v_p   = (float*)(base + o); o += NELPS * 4;
  short* qsh = (short*)(base + o); o += NELPS * 2;
  short* qsl = (short*)(base + o); o += NELPS * 2;
  short* ksh = (short*)(base + o); o += NELPS * 2;
  short* ksl = (short*)(base + o); o += NELPS * 2;
  short* imgh = (short*)(base + o); o += NELPS * 2;
  short* imgl = (short*)(base + o); o += NELPS * 2;
  short* Woh = (short*)(base + o); o += WEL * 2;
  short* Wol = (short*)(base + o); o += WEL * 2;

  // 1) projections + weight splits
  ProjArgs p;
  p.X[0] = queries; p.X[1] = keys; p.X[2] = values;
  p.W[0] = Wq;      p.W[1] = Wk;   p.W[2] = Wv;
  p.bias[0] = bq;   p.bias[1] = bk; p.bias[2] = bv;
  p.Cf[0] = q_sig;  p.Cf[1] = k_p;  p.Cf[2] = v_p;
  p.Ch[0] = qsh; p.Cl[0] = qsl;
  p.Ch[1] = ksh; p.Cl[1] = ksl;
  p.Ch[2] = nullptr; p.Cl[2] = nullptr;
  p.Wo = Wo; p.Woh = Woh; p.Wol = Wol;
  proj_kernel<<<dim3(13, HD/64, 3), 512, 0, stream>>>(p);

  // 2) fused scores + softmax + gated PV -> image (d-split: 832 blocks)
  attn_fused<<<dim3(13, NH, BATCH * 2), 512, 0, stream>>>(
      qsh, qsl, ksh, ksl, q_sig, k_p, v_p, scale, imgh, imgl);

  // 3) out = image @ Wo^T + bo, gated by q_sig
  out_kernel<<<dim3(MPAD/32, HD/64), 512, 0, stream>>>(
      imgh, imgl, Woh, Wol, bo, q_sig, (float*)d_out);
}

// Round 10
// 128.893 us; speedup vs baseline: 1.0751x; 1.0501x over previous
//
#include <hip/hip_runtime.h>
#include <hip/hip_bf16.h>
#include <math.h>

#define NQ 196
#define BATCH 4
#define HD 512            // H * D_K == D_MODEL
#define NH 8
#define DK 64
#define MROWS 784         // BATCH*NQ
#define MPAD 832          // 26*32: GEMM M-tile overhang rows

typedef __attribute__((ext_vector_type(8))) short short8;
typedef __attribute__((ext_vector_type(4))) short short4v;
typedef __attribute__((ext_vector_type(4))) float float4v;

__device__ __forceinline__ float b2f(short s) {
  return __uint_as_float(((unsigned)(unsigned short)s) << 16);
}
__device__ __forceinline__ short f2b(float x) {
  return __builtin_bit_cast(short, __float2bfloat16(x));
}
__device__ __forceinline__ float fexp2(float x) {
  float r; asm("v_exp_f32 %0, %1" : "=v"(r) : "v"(x)); return r;
}
__device__ __forceinline__ float frcp(float x) {
  float r; asm("v_rcp_f32 %0, %1" : "=v"(r) : "v"(x)); return r;
}
__device__ __forceinline__ void cvt4(float4 v, short4v& hi, short4v& lo) {
  float x[4] = {v.x, v.y, v.z, v.w};
  #pragma unroll
  for (int i = 0; i < 4; ++i) {
    hi[i] = f2b(x[i]);
    lo[i] = f2b(x[i] - b2f(hi[i]));
  }
}
__device__ __forceinline__ void cvt8(float4 v0, float4 v1, short8& hi, short8& lo) {
  short4v h0, l0, h1, l1;
  cvt4(v0, h0, l0); cvt4(v1, h1, l1);
  hi = short8{h0[0],h0[1],h0[2],h0[3],h1[0],h1[1],h1[2],h1[3]};
  lo = short8{l0[0],l0[1],l0[2],l0[3],l1[0],l1[1],l1[2],l1[3]};
}
__device__ __forceinline__ void gload_lds16(const void* g, void* l) {
  __builtin_amdgcn_global_load_lds(
      (const __attribute__((address_space(1))) unsigned int*)g,
      (__attribute__((address_space(3))) unsigned int*)l, 16, 0, 0);
}

// ==================== kernel 1: projections (q/k/v) =========================
// 32x64 tile, BK=64 (624 blocks, 2.44/CU for tail balance). A=X fp32 (t<256),
// B=W fp32 (all threads), reg-staged->bf16 hi/lo. 48 KB LDS, 3 blocks/CU.
// Spare z==2 blocks also split Wo -> bf16 hi/lo for kernel 3. (R8-verified.)
struct ProjArgs {
  const float* X[3]; const float* W[3]; const float* bias[3];
  float* Cf[3]; short* Ch[3]; short* Cl[3];
  const float* Wo; short* Woh; short* Wol;
};

__global__ __launch_bounds__(512)
void proj_kernel(ProjArgs a) {
  const int z = blockIdx.z;
  const float* __restrict__ X = a.X[z];
  const float* __restrict__ W = a.W[z];
  const int t = threadIdx.x;
  const int ln = t & 63, lm = ln & 15, quad = ln >> 4;
  const int w = t >> 6, wm = w >> 2, wn = w & 3;     // 2m x 4n waves, 16x16 out
  const int m0 = blockIdx.x << 5, n0 = blockIdx.y << 6;

  __shared__ __align__(16) short smem[24576];  // 48 KB: 2 buf x {Ah2k Al2k Bh4k Bl4k shorts}

  // A staging: t<256, row ra 0..31, 8 floats each.
  const bool aload = t < 256;
  const int ra = (t & 255) >> 3;
  const int cga = (t & 7) << 3;
  const int wIdxA = ra * 64 + (cga ^ ((ra & 7) << 3));
  const float* gA = X + (size_t)min(m0 + ra, MROWS - 1) * HD;   // clamp overhang
  // B staging: all 512 threads, row sr 0..63, 8 floats each.
  const int sr = t >> 3;
  const int cgb = (t & 7) << 3;
  const int wIdxB = sr * 64 + (cgb ^ ((sr & 7) << 3));
  const float* gB = W + (size_t)(n0 + sr) * HD;

  float4 ra0, ra1, rb0, rb1;
  float4v acc = {0.f,0.f,0.f,0.f};
  const int ar = (wm << 4) + lm;                // A tile row (0..31)
  const int br = (wn << 4) + lm;                // B tile row (0..63)
  const int swz = (lm & 7) << 3;

  // prologue: stage buffer 0
  if (aload) { ra0 = *(const float4*)(gA + cga);  ra1 = *(const float4*)(gA + cga + 4); }
  rb0 = *(const float4*)(gB + cgb);  rb1 = *(const float4*)(gB + cgb + 4);
  {
    short8 hi, lo;
    if (aload) {
      cvt8(ra0, ra1, hi, lo);
      *(short8*)&smem[0 + wIdxA] = hi;  *(short8*)&smem[2048 + wIdxA] = lo;
    }
    cvt8(rb0, rb1, hi, lo);
    *(short8*)&smem[4096 + wIdxB] = hi;  *(short8*)&smem[8192 + wIdxB] = lo;
  }

  for (int kt = 0; kt < 8; ++kt) {
    const int buf = (kt & 1) * 12288;
    __syncthreads();                            // buf(kt) ready
    if (kt < 7) {
      const int kb = (kt + 1) << 6;
      if (aload) { ra0 = *(const float4*)(gA + kb + cga);  ra1 = *(const float4*)(gA + kb + cga + 4); }
      rb0 = *(const float4*)(gB + kb + cgb);  rb1 = *(const float4*)(gB + kb + cgb + 4);
    }
    const short* Sb = smem + buf;
    #pragma unroll
    for (int h2 = 0; h2 < 2; ++h2) {
      const int c = (h2 << 5) + (quad << 3);
      const int cs = c ^ swz;
      short8 a_h = *(const short8*)&Sb[         ar * 64 + cs];
      short8 a_l = *(const short8*)&Sb[2048  +  ar * 64 + cs];
      short8 b_h = *(const short8*)&Sb[4096  +  br * 64 + cs];
      short8 b_l = *(const short8*)&Sb[8192  +  br * 64 + cs];
      acc = __builtin_amdgcn_mfma_f32_16x16x32_bf16(a_h, b_h, acc, 0,0,0);
      acc = __builtin_amdgcn_mfma_f32_16x16x32_bf16(a_h, b_l, acc, 0,0,0);
      acc = __builtin_amdgcn_mfma_f32_16x16x32_bf16(a_l, b_h, acc, 0,0,0);
    }
    if (kt < 7) {
      short* Nb = smem + (buf ^ 12288);
      short8 hi, lo;
      if (aload) {
        cvt8(ra0, ra1, hi, lo);
        *(short8*)&Nb[0 + wIdxA] = hi;  *(short8*)&Nb[2048 + wIdxA] = lo;
      }
      cvt8(rb0, rb1, hi, lo);
      *(short8*)&Nb[4096 + wIdxB] = hi;  *(short8*)&Nb[8192 + wIdxB] = lo;
    }
  }

  // epilogue: bias, fp32 store (+ bf16 hi/lo split for q/k)
  {
    const float* bias = a.bias[z];
    float* Cf = a.Cf[z]; short* Ch = a.Ch[z]; short* Cl = a.Cl[z];
    const int n = n0 + (wn << 4) + lm;
    const float bv = bias[n];
    #pragma unroll
    for (int r = 0; r < 4; ++r) {
      const int m = m0 + (wm << 4) + (quad << 2) + r;   // < MPAD always
      const float c = acc[r] + bv;
      Cf[(size_t)m * HD + n] = c;
      if (Ch) {
        const short hi = f2b(c);
        Ch[(size_t)m * HD + n] = hi;
        Cl[(size_t)m * HD + n] = f2b(c - b2f(hi));
      }
    }
  }

  // Wo split (64 of the 208 z==2 blocks; independent of the GEMM above)
  if (z == 2) {
    const int lin = blockIdx.y * 26 + blockIdx.x;
    if (lin < 64) {
      const size_t off = (size_t)lin * 4096 + (size_t)t * 8;
      float4 v0 = *(const float4*)(a.Wo + off);
      float4 v1 = *(const float4*)(a.Wo + off + 4);
      short8 hi, lo; cvt8(v0, v1, hi, lo);
      *(short8*)(a.Woh + off) = hi;
      *(short8*)(a.Wol + off) = lo;
    }
  }
}

// ======== kernel 2: fused attention (scores MFMA + softmax + gated PV) ======
// One block per (q-tile 16, h, b); 8 waves. Phase 3: wave = (4 q-rows, k-half)
// -> R is only [2][16][64] (8 KB), LDS 21.3 KB.  (R6-proven, 131.18 config.)
__global__ __launch_bounds__(512)
void attn_fused(const short* __restrict__ qsh, const short* __restrict__ qsl,
                const short* __restrict__ ksh, const short* __restrict__ ksl,
                const float* __restrict__ qsg, const float* __restrict__ kpg,
                const float* __restrict__ vpg, const float* __restrict__ scg,
                short* __restrict__ imgh, short* __restrict__ imgl) {
  const int q0 = blockIdx.x * 16;
  const int h  = blockIdx.y;
  const int b  = blockIdx.z;
  const int t  = threadIdx.x;
  const int w = t >> 6, ln = t & 63;
  const int lm = ln & 15, quad = ln >> 4;
  const float L2E = 1.4426950408889634f;

  __shared__ __align__(16) float S[16][212];  // 13.6 KB (16B-aligned rows)
  __shared__ float R2[2][16][64];             // 8 KB: k-half partials

  // ---- phase 1: S = q_sig . k_p^T (bf16x3 MFMA), waves stride nt by 8 ----
  const size_t abase = ((size_t)(b * NQ) + q0 + lm) * HD + h * DK + (quad << 3);
  short8 ah0 = *(const short8*)(qsh + abase);
  short8 ah1 = *(const short8*)(qsh + abase + 32);
  short8 al0 = *(const short8*)(qsl + abase);
  short8 al1 = *(const short8*)(qsl + abase + 32);

  for (int nt = w; nt < 13; nt += 8) {
    const size_t bbase = ((size_t)(b * NQ) + nt * 16 + lm) * HD + h * DK + (quad << 3);
    short8 bh0 = *(const short8*)(ksh + bbase);
    short8 bh1 = *(const short8*)(ksh + bbase + 32);
    short8 bl0 = *(const short8*)(ksl + bbase);
    short8 bl1 = *(const short8*)(ksl + bbase + 32);
    float4v acc = {0.f, 0.f, 0.f, 0.f};
    acc = __builtin_amdgcn_mfma_f32_16x16x32_bf16(ah0, bh0, acc, 0,0,0);
    acc = __builtin_amdgcn_mfma_f32_16x16x32_bf16(ah1, bh1, acc, 0,0,0);
    acc = __builtin_amdgcn_mfma_f32_16x16x32_bf16(ah0, bl0, acc, 0,0,0);
    acc = __builtin_amdgcn_mfma_f32_16x16x32_bf16(ah1, bl1, acc, 0,0,0);
    acc = __builtin_amdgcn_mfma_f32_16x16x32_bf16(al0, bh0, acc, 0,0,0);
    acc = __builtin_amdgcn_mfma_f32_16x16x32_bf16(al1, bh1, acc, 0,0,0);
    #pragma unroll
    for (int r = 0; r < 4; ++r)
      S[(quad << 2) + r][nt * 16 + lm] = acc[r];
  }
  __syncthreads();

  // ---- phase 2: softmax in place (wave w: rows 2w, 2w+1) ----
  for (int i = 0; i < 2; ++i) {
    const int rr = (w << 1) + i;
    const int q = q0 + rr;
    const bool qok = q < NQ;
    const float* srow = scg + ((size_t)h * NQ + (qok ? q : 0)) * NQ;
    float att[4];
    #pragma unroll
    for (int j = 0; j < 4; ++j) {
      const int c = ln + (j << 6);
      att[j] = -1e30f;
      if (c < NQ) att[j] = S[rr][c] * srow[c] * L2E;
    }
    float m = fmaxf(fmaxf(att[0], att[1]), fmaxf(att[2], att[3]));
    #pragma unroll
    for (int off = 32; off; off >>= 1) m = fmaxf(m, __shfl_xor(m, off, 64));
    float e[4], s = 0.f;
    #pragma unroll
    for (int j = 0; j < 4; ++j) { e[j] = fexp2(att[j] - m); s += e[j]; }
    #pragma unroll
    for (int off = 32; off; off >>= 1) s += __shfl_xor(s, off, 64);
    const float rinv = __fdividef(1.f, s);
    #pragma unroll
    for (int j = 0; j < 4; ++j) {
      const int c = ln + (j << 6);
      if (c < NQ) S[rr][c] = e[j] * rinv;
    }
  }
  __syncthreads();

  // ---- phase 3: gated PV. wave w -> q-rows (w>>1)*4..+3, k-half (w&1). ----
  // k ranges [0,100) and [100,196): 4-aligned so S reads stay ds_read_b128.
  {
    const int d = ln;
    const int qg = (w >> 1) << 2;               // 0,4,8,12
    const int kh = w & 1;
    const int kbeg = kh ? 100 : 0;
    const int kend = kh ? 196 : 100;
    const float LOG2E = 1.4426950408889634f;

    float nqs[4];
    #pragma unroll
    for (int qi = 0; qi < 4; ++qi) {
      const int row = min(b * NQ + q0 + qg + qi, MROWS - 1);  // clamp overhang
      nqs[qi] = -qsg[(size_t)row * HD + h * DK + d] * LOG2E;
    }
    const float* kp = kpg + ((size_t)(b * NQ)) * HD + h * DK + d;
    const float* vp = vpg + ((size_t)(b * NQ)) * HD + h * DK + d;

    float acc[4] = {0.f, 0.f, 0.f, 0.f};

    for (int k = kbeg; k < kend; k += 4) {
      const float kv0 = kp[(size_t)(k + 0) * HD];
      const float kv1 = kp[(size_t)(k + 1) * HD];
      const float kv2 = kp[(size_t)(k + 2) * HD];
      const float kv3 = kp[(size_t)(k + 3) * HD];
      const float vv0 = vp[(size_t)(k + 0) * HD];
      const float vv1 = vp[(size_t)(k + 1) * HD];
      const float vv2 = vp[(size_t)(k + 2) * HD];
      const float vv3 = vp[(size_t)(k + 3) * HD];
      #pragma unroll
      for (int qi = 0; qi < 4; ++qi) {
        const float4 s4 = *(const float4*)&S[qg + qi][k];
        acc[qi] += s4.x * (vv0 * frcp(1.f + fexp2(nqs[qi] * kv0)));
        acc[qi] += s4.y * (vv1 * frcp(1.f + fexp2(nqs[qi] * kv1)));
        acc[qi] += s4.z * (vv2 * frcp(1.f + fexp2(nqs[qi] * kv2)));
        acc[qi] += s4.w * (vv3 * frcp(1.f + fexp2(nqs[qi] * kv3)));
      }
    }
    #pragma unroll
    for (int qi = 0; qi < 4; ++qi) R2[kh][qg + qi][d] = acc[qi];
  }
  __syncthreads();

  // reduce the 2 k-halves, write image as bf16 hi/lo
  #pragma unroll
  for (int j = 0; j < 2; ++j) {
    const int idx = t + (j << 9);
    const int qi = idx >> 6, dd = idx & 63;
    const int q = q0 + qi;
    if (q < NQ) {
      const float s = R2[0][qi][dd] + R2[1][qi][dd];
      const size_t o = ((size_t)(b * NQ) + q) * HD + h * DK + dd;
      const short hi = f2b(s);
      imgh[o] = hi;
      imgl[o] = f2b(s - b2f(hi));
    }
  }
}

// ======== kernel 3: out = image @ Wo^T + bo, gated; all-DMA 32x64 tile ======
// 208 blocks (26 m-tiles x 8 n-tiles); 48 KB LDS.  (R6-proven version.)
__global__ __launch_bounds__(512)
void out_kernel(const short* __restrict__ Ahp, const short* __restrict__ Alp,
                const short* __restrict__ Bhp, const short* __restrict__ Blp,
                const float* __restrict__ bo, const float* __restrict__ q_sig,
                float* __restrict__ out) {
  __shared__ short smem[24576];      // 48 KB: 2 buf x {Ah 2k, Al 2k, Bh 4k, Bl 4k}
  const int t = threadIdx.x;
  const int ln = t & 63, lm = ln & 15, quad = ln >> 4;
  const int w = t >> 6;
  const int wm = w >> 2, wn = w & 3;           // 2m x 4n waves, 16x16 out each
  const int m0 = blockIdx.x << 5, n0 = blockIdx.y << 6;

  // B staging: all 512 threads, row sr=t>>3, pre-swizzled source col.
  const int sr = t >> 3;
  const int sc = ((t & 7) ^ (sr & 7)) << 3;
  const short* gB_h = Bhp + (size_t)(n0 + sr) * HD + sc;
  const short* gB_l = Blp + (size_t)(n0 + sr) * HD + sc;
  // A staging: waves 0-3 hi, waves 4-7 lo; row ra=tt>>3 (0..31).
  const int tt = t & 255;
  const int ra = tt >> 3;
  const int sca = ((tt & 7) ^ (ra & 7)) << 3;
  const short* gA = ((t < 256) ? Ahp : Alp) + (size_t)(m0 + ra) * HD + sca;
  const int aoff = (t < 256) ? 0 : 2048;        // Ah / Al base (shorts)
  const int ldstA = aoff + tt * 8;
  const int ldstB = t * 8;

  float4v acc = {0.f,0.f,0.f,0.f};

  gload_lds16(gA,   &smem[ldstA]);
  gload_lds16(gB_h, &smem[4096 + ldstB]);
  gload_lds16(gB_l, &smem[8192 + ldstB]);

  const int ar = (wm << 4) + lm;                // A tile row (0..31)
  const int br = (wn << 4) + lm;                // B tile row (0..63)
  const int swz = (lm & 7) << 3;

  for (int kt = 0; kt < 8; ++kt) {
    const int buf = kt & 1;
    __syncthreads();                            // buf ready (DMA drained)
    if (kt < 7) {
      const int kb = (kt + 1) << 6;
      short* nb = &smem[(buf ^ 1) * 12288];
      gload_lds16(gA + kb,   &nb[ldstA]);
      gload_lds16(gB_h + kb, &nb[4096 + ldstB]);
      gload_lds16(gB_l + kb, &nb[8192 + ldstB]);
    }
    const short* Sb = &smem[buf * 12288];
    #pragma unroll
    for (int h2 = 0; h2 < 2; ++h2) {
      const int c = (h2 << 5) + (quad << 3);
      const int cs = c ^ swz;
      short8 a_h = *(const short8*)&Sb[         ar * 64 + cs];
      short8 a_l = *(const short8*)&Sb[2048  +  ar * 64 + cs];
      short8 b_h = *(const short8*)&Sb[4096  +  br * 64 + cs];
      short8 b_l = *(const short8*)&Sb[8192  +  br * 64 + cs];
      acc = __builtin_amdgcn_mfma_f32_16x16x32_bf16(a_h, b_h, acc, 0,0,0);
      acc = __builtin_amdgcn_mfma_f32_16x16x32_bf16(a_h, b_l, acc, 0,0,0);
      acc = __builtin_amdgcn_mfma_f32_16x16x32_bf16(a_l, b_h, acc, 0,0,0);
    }
  }

  {
    const int n = n0 + (wn << 4) + lm;
    const float bv = bo[n];
    #pragma unroll
    for (int r = 0; r < 4; ++r) {
      const int m = m0 + (wm << 4) + (quad << 2) + r;
      if (m < MROWS) {
        float c = acc[r] + bv;
        const float qg = q_sig[(size_t)m * HD + n];
        c = __fdividef(c, 1.f + __expf(-qg * c));  // sigmoid(qg*c)*c
        out[(size_t)m * HD + n] = c;
      }
    }
  }
}

extern "C" void kernel_launch(void* const* d_in, const int* in_sizes, int n_in,
                              void* d_out, int out_size, void* d_ws, size_t ws_size,
                              hipStream_t stream) {
  const float* queries = (const float*)d_in[0];
  const float* keys    = (const float*)d_in[1];
  const float* values  = (const float*)d_in[2];
  const float* Wq = (const float*)d_in[3];
  const float* bq = (const float*)d_in[4];
  const float* Wk = (const float*)d_in[5];
  const float* bk = (const float*)d_in[6];
  const float* Wv = (const float*)d_in[7];
  const float* bv = (const float*)d_in[8];
  const float* Wo = (const float*)d_in[9];
  const float* bo = (const float*)d_in[10];
  const float* scale = (const float*)d_in[11];

  char* base = (char*)d_ws;
  const size_t NELPS = (size_t)MPAD * HD;    // 425984
  const size_t WEL   = (size_t)HD * HD;      // 262144

  size_t o = 0;
  float* q_sig = (float*)(base + o); o += NELPS * 4;
  float* k_p   = (float*)(base + o); o += NELPS * 4;
  float* v_p   = (float*)(base + o); o += NELPS * 4;
  short* qsh = (short*)(base + o); o += NELPS * 2;
  short* qsl = (short*)(base + o); o += NELPS * 2;
  short* ksh = (short*)(base + o); o += NELPS * 2;
  short* ksl = (short*)(base + o); o += NELPS * 2;
  short* imgh = (short*)(base + o); o += NELPS * 2;
  short* imgl = (short*)(base + o); o += NELPS * 2;
  short* Woh = (short*)(base + o); o += WEL * 2;
  short* Wol = (short*)(base + o); o += WEL * 2;

  // 1) projections + weight splits (624 blocks)
  ProjArgs p;
  p.X[0] = queries; p.X[1] = keys; p.X[2] = values;
  p.W[0] = Wq;      p.W[1] = Wk;   p.W[2] = Wv;
  p.bias[0] = bq;   p.bias[1] = bk; p.bias[2] = bv;
  p.Cf[0] = q_sig;  p.Cf[1] = k_p;  p.Cf[2] = v_p;
  p.Ch[0] = qsh; p.Cl[0] = qsl;
  p.Ch[1] = ksh; p.Cl[1] = ksl;
  p.Ch[2] = nullptr; p.Cl[2] = nullptr;
  p.Wo = Wo; p.Woh = Woh; p.Wol = Wol;
  proj_kernel<<<dim3(MPAD/32, HD/64, 3), 512, 0, stream>>>(p);

  // 2) fused scores + softmax + gated PV -> image (bf16 hi/lo)  [R6 best]
  attn_fused<<<dim3(13, NH, BATCH), 512, 0, stream>>>(
      qsh, qsl, ksh, ksl, q_sig, k_p, v_p, scale, imgh, imgl);

  // 3) out = image @ Wo^T + bo, gated by q_sig  [R6 best]
  out_kernel<<<dim3(MPAD/32, HD/64), 512, 0, stream>>>(
      imgh, imgl, Woh, Wol, bo, q_sig, (float*)d_out);
}